// Round 7
// baseline (35.027 us; speedup 1.0000x reference)
//
#include <hip/hip_runtime.h>
#include <math.h>

#define EPS_CLIP 1e-6f
#define WPB 4      // b's per wave
#define NWAVES 4   // waves per block

struct F3 { float x, y, z; };   // 12 B -> global_load_dwordx3

// SS = compile-time S (0 -> runtime S_rt)
template <int SS>
__global__ __launch_bounds__(256) void sym_loss_kernel(
    const float* __restrict__ R_pred,   // (B, 64, 3, 3)
    const float* __restrict__ R_gt,     // (B, 3, 3)
    const float* __restrict__ rot,      // (S, 3, 3)
    float* __restrict__ partial,        // (gridDim.x,)
    int S_rt)
{
    const int S    = SS ? SS : S_rt;
    const int tid  = threadIdx.x;
    const int lane = tid & 63;
    const int wid  = tid >> 6;
    const int gw   = __builtin_amdgcn_readfirstlane(blockIdx.x * NWAVES + wid);
    const int b0   = gw * WPB;

    // per-lane base: candidate `lane` of rotation b0 (3 F3 rows); next b = +192 F3
    const F3* base = reinterpret_cast<const F3*>(R_pred) + ((size_t)b0 * 64 + lane) * 3;

    // ---- 3-slot register ring, prefetch distance 2 (72 B/lane in flight) ----
    F3 A[3][3];
    #pragma unroll
    for (int r = 0; r < 3; ++r) A[0][r] = base[r];
    #pragma unroll
    for (int r = 0; r < 3; ++r) A[1][r] = base[192 + r];

    float mk[WPB];
    #pragma unroll
    for (int k = 0; k < WPB; ++k) {
        // issue load for k+2 before computing k
        if (k + 2 < WPB) {
            #pragma unroll
            for (int r = 0; r < 3; ++r)
                A[(k + 2) % 3][r] = base[(size_t)(k + 2) * 192 + r];
        }
        const int slot = k % 3;       // compile-time after unroll
        const int b = b0 + k;         // wave-uniform

        // G: wave-uniform address -> scalar loads
        const float* G = R_gt + (size_t)b * 9;
        float g[9];
        #pragma unroll
        for (int e = 0; e < 9; ++e) g[e] = G[e];

        const float p[9] = { A[slot][0].x, A[slot][0].y, A[slot][0].z,
                             A[slot][1].x, A[slot][1].y, A[slot][1].z,
                             A[slot][2].x, A[slot][2].y, A[slot][2].z };

        // Q = P * G^T (27 FMA);  trace(P @ (rot_s @ G)^T) = <Q, rot_s>  (cyclic trace)
        float q[9];
        #pragma unroll
        for (int i = 0; i < 3; ++i)
            #pragma unroll
            for (int j = 0; j < 3; ++j)
                q[i * 3 + j] = fmaf(p[i * 3 + 0], g[j * 3 + 0],
                               fmaf(p[i * 3 + 1], g[j * 3 + 1],
                                    p[i * 3 + 2] * g[j * 3 + 2]));

        // S trace-dots against rot (grid-uniform -> SGPRs)
        float m = -1e30f;
        if (SS) {
            #pragma unroll
            for (int s = 0; s < SS; ++s) {
                const float* Rs = rot + s * 9;
                float tr = 0.f;
                #pragma unroll
                for (int e = 0; e < 9; ++e) tr = fmaf(q[e], Rs[e], tr);
                m = fmaxf(m, tr);
            }
        } else {
            for (int s = 0; s < S; ++s) {
                const float* Rs = rot + s * 9;
                float tr = 0.f;
                #pragma unroll
                for (int e = 0; e < 9; ++e) tr = fmaf(q[e], Rs[e], tr);
                m = fmaxf(m, tr);
            }
        }

        // max over the 64 candidate lanes
        #pragma unroll
        for (int off = 32; off; off >>= 1) m = fmaxf(m, __shfl_xor(m, off));
        mk[k] = m;   // every lane holds the wave max
    }

    // ---- batched acos: lanes 0..3 each take one wave max, single acosf ----
    float mv = mk[0];
    #pragma unroll
    for (int k = 1; k < WPB; ++k) mv = (lane == k) ? mk[k] : mv;
    float cosv = (mv - 1.0f) * 0.5f;
    cosv = fminf(fmaxf(cosv, -1.0f + EPS_CLIP), 1.0f - EPS_CLIP);
    float a = (lane < WPB) ? acosf(cosv) : 0.0f;  // min over (c,s) arccos == arccos(max trace)
    a += __shfl_xor(a, 1);
    a += __shfl_xor(a, 2);

    __shared__ float sLoss[NWAVES];
    if (lane == 0) sLoss[wid] = a;
    __syncthreads();
    if (tid == 0) {
        float sum = 0.f;
        #pragma unroll
        for (int i = 0; i < NWAVES; ++i) sum += sLoss[i];
        partial[blockIdx.x] = sum;
    }
}

__global__ __launch_bounds__(1024) void reduce_kernel(
    const float* __restrict__ partial, int n, float* __restrict__ out, float invB)
{
    float sum = 0.f;
    for (int i = threadIdx.x; i < n; i += 1024) sum += partial[i];
    #pragma unroll
    for (int off = 32; off; off >>= 1) sum += __shfl_xor(sum, off);
    __shared__ float ws[16];
    const int w = threadIdx.x >> 6;
    if ((threadIdx.x & 63) == 0) ws[w] = sum;
    __syncthreads();
    if (threadIdx.x == 0) {
        float t = 0.f;
        #pragma unroll
        for (int i = 0; i < 16; ++i) t += ws[i];
        out[0] = t * invB;
    }
}

extern "C" void kernel_launch(void* const* d_in, const int* in_sizes, int n_in,
                              void* d_out, int out_size, void* d_ws, size_t ws_size,
                              hipStream_t stream) {
    const float* R_pred = (const float*)d_in[0];
    const float* R_gt   = (const float*)d_in[1];
    const float* rot    = (const float*)d_in[2];
    float* out = (float*)d_out;

    const int B = in_sizes[1] / 9;                 // 32768
    const int S = in_sizes[2] / 9;                 // 12
    const int nBlocks = B / (WPB * NWAVES);        // 2048

    float* partial = (float*)d_ws;                 // nBlocks * 4 B

    // === DECOMPOSITION EXPERIMENT: main kernel launched TWICE (identical) ===
    // Second launch rewrites identical partials (deterministic). The delta
    // total_R7 - total_R6 measures the warm main-kernel duration directly.
    if (S == 12) {
        sym_loss_kernel<12><<<nBlocks, 256, 0, stream>>>(R_pred, R_gt, rot, partial, S);
        sym_loss_kernel<12><<<nBlocks, 256, 0, stream>>>(R_pred, R_gt, rot, partial, S);
    } else {
        sym_loss_kernel<0><<<nBlocks, 256, 0, stream>>>(R_pred, R_gt, rot, partial, S);
        sym_loss_kernel<0><<<nBlocks, 256, 0, stream>>>(R_pred, R_gt, rot, partial, S);
    }

    reduce_kernel<<<1, 1024, 0, stream>>>(partial, nBlocks, out, 1.0f / (float)B);
}

// Round 8
// 25.013 us; speedup vs baseline: 1.4003x; 1.4003x over previous
//
#include <hip/hip_runtime.h>
#include <math.h>

#define EPS_CLIP 1e-6f
#define WPB 4      // b's per wave
#define NWAVES 4   // waves per block

typedef float v2f __attribute__((ext_vector_type(2)));

#if __has_builtin(__builtin_elementwise_fma)
#define PK_FMA(a, b, c) __builtin_elementwise_fma((a), (b), (c))
#else
static __device__ __forceinline__ v2f PK_FMA(v2f a, v2f b, v2f c) {
    v2f r; r.x = fmaf(a.x, b.x, c.x); r.y = fmaf(a.y, b.y, c.y); return r;
}
#endif

// SS = compile-time S (0 -> runtime S_rt)
template <int SS>
__global__ __launch_bounds__(256) void sym_loss_kernel(
    const float* __restrict__ R_pred,   // (B, 64, 3, 3)
    const float* __restrict__ R_gt,     // (B, 3, 3)
    const float* __restrict__ rot,      // (S, 3, 3)
    float* __restrict__ partial,        // (gridDim.x,)
    int S_rt)
{
    const int S    = SS ? SS : S_rt;
    const int tid  = threadIdx.x;
    const int lane = tid & 63;
    const int wid  = tid >> 6;
    const int gw   = __builtin_amdgcn_readfirstlane(blockIdx.x * NWAVES + wid);
    const int b0   = gw * WPB;

    // wave-private transpose tile: one b (576 dwords) per wave. No barriers —
    // DS ops from a single wave complete in order, so write->read is safe.
    __shared__ float tile[NWAVES][576];
    float* __restrict__ T = tile[wid];

    const float* wsrc = R_pred + (size_t)b0 * 576;

    // ---- coalesced prefetch of b0: lane l owns dwords {4l..4l+3},{256+4l..},{512+l}
    float4 ra = *reinterpret_cast<const float4*>(wsrc + 4 * lane);
    float4 rb = *reinterpret_cast<const float4*>(wsrc + 256 + 4 * lane);
    float  rc = wsrc[512 + lane];

    float mk[WPB];
    #pragma unroll
    for (int k = 0; k < WPB; ++k) {
        // stage current b into wave-private LDS (coalesced b128 writes)
        *reinterpret_cast<float4*>(T + 4 * lane)       = ra;
        *reinterpret_cast<float4*>(T + 256 + 4 * lane) = rb;
        T[512 + lane] = rc;

        // issue next b's coalesced loads (latency hides under compute below)
        if (k + 1 < WPB) {
            const float* nsrc = wsrc + (size_t)(k + 1) * 576;
            ra = *reinterpret_cast<const float4*>(nsrc + 4 * lane);
            rb = *reinterpret_cast<const float4*>(nsrc + 256 + 4 * lane);
            rc = nsrc[512 + lane];
        }

        // candidate = lane: 9 floats at dword offset 9*lane (+e).
        // stride 9 (odd) -> exactly 2 lanes/bank per wave = conflict-free.
        float p[9];
        #pragma unroll
        for (int e = 0; e < 9; ++e) p[e] = T[9 * lane + e];

        const int b = b0 + k;                     // wave-uniform
        const float* G = R_gt + (size_t)b * 9;    // -> scalar s_loads
        float g[9];
        #pragma unroll
        for (int e = 0; e < 9; ++e) g[e] = G[e];

        // Q = P * G^T (27 FMA);  trace(P @ (rot_s @ G)^T) = <Q, rot_s>
        float q[9];
        #pragma unroll
        for (int i = 0; i < 3; ++i)
            #pragma unroll
            for (int j = 0; j < 3; ++j)
                q[i * 3 + j] = fmaf(p[i * 3 + 0], g[j * 3 + 0],
                               fmaf(p[i * 3 + 1], g[j * 3 + 1],
                                    p[i * 3 + 2] * g[j * 3 + 2]));

        // packed element-pair dots: 4 pk_fma + 1 add + 1 fma per sym op
        const v2f q01 = {q[0], q[1]}, q23 = {q[2], q[3]},
                  q45 = {q[4], q[5]}, q67 = {q[6], q[7]};
        const float q8 = q[8];

        float m = -1e30f;
        if (SS) {
            #pragma unroll
            for (int s = 0; s < SS; ++s) {
                const float* Rs = rot + s * 9;
                const v2f r01 = {Rs[0], Rs[1]}, r23 = {Rs[2], Rs[3]},
                          r45 = {Rs[4], Rs[5]}, r67 = {Rs[6], Rs[7]};
                v2f acc = q01 * r01;
                acc = PK_FMA(q23, r23, acc);
                acc = PK_FMA(q45, r45, acc);
                acc = PK_FMA(q67, r67, acc);
                const float tr = fmaf(q8, Rs[8], acc.x + acc.y);
                m = fmaxf(m, tr);
            }
        } else {
            for (int s = 0; s < S; ++s) {
                const float* Rs = rot + s * 9;
                float tr = 0.f;
                #pragma unroll
                for (int e = 0; e < 9; ++e) tr = fmaf(q[e], Rs[e], tr);
                m = fmaxf(m, tr);
            }
        }

        // max over the 64 candidate lanes
        #pragma unroll
        for (int off = 32; off; off >>= 1) m = fmaxf(m, __shfl_xor(m, off));
        mk[k] = m;
    }

    // ---- batched acos: lanes 0..3 take one wave max each, single acosf ----
    float mv = mk[0];
    #pragma unroll
    for (int k = 1; k < WPB; ++k) mv = (lane == k) ? mk[k] : mv;
    float cosv = (mv - 1.0f) * 0.5f;
    cosv = fminf(fmaxf(cosv, -1.0f + EPS_CLIP), 1.0f - EPS_CLIP);
    float a = (lane < WPB) ? acosf(cosv) : 0.0f;  // min over (c,s) arccos == arccos(max trace)
    a += __shfl_xor(a, 1);
    a += __shfl_xor(a, 2);

    __shared__ float sLoss[NWAVES];
    if (lane == 0) sLoss[wid] = a;
    __syncthreads();
    if (tid == 0) {
        float sum = 0.f;
        #pragma unroll
        for (int i = 0; i < NWAVES; ++i) sum += sLoss[i];
        partial[blockIdx.x] = sum;
    }
}

__global__ __launch_bounds__(1024) void reduce_kernel(
    const float* __restrict__ partial, int n, float* __restrict__ out, float invB)
{
    float sum = 0.f;
    for (int i = threadIdx.x; i < n; i += 1024) sum += partial[i];
    #pragma unroll
    for (int off = 32; off; off >>= 1) sum += __shfl_xor(sum, off);
    __shared__ float ws[16];
    const int w = threadIdx.x >> 6;
    if ((threadIdx.x & 63) == 0) ws[w] = sum;
    __syncthreads();
    if (threadIdx.x == 0) {
        float t = 0.f;
        #pragma unroll
        for (int i = 0; i < 16; ++i) t += ws[i];
        out[0] = t * invB;
    }
}

extern "C" void kernel_launch(void* const* d_in, const int* in_sizes, int n_in,
                              void* d_out, int out_size, void* d_ws, size_t ws_size,
                              hipStream_t stream) {
    const float* R_pred = (const float*)d_in[0];
    const float* R_gt   = (const float*)d_in[1];
    const float* rot    = (const float*)d_in[2];
    float* out = (float*)d_out;

    const int B = in_sizes[1] / 9;                 // 32768
    const int S = in_sizes[2] / 9;                 // 12
    const int nBlocks = B / (WPB * NWAVES);        // 2048

    float* partial = (float*)d_ws;                 // nBlocks * 4 B

    if (S == 12)
        sym_loss_kernel<12><<<nBlocks, 256, 0, stream>>>(R_pred, R_gt, rot, partial, S);
    else
        sym_loss_kernel<0><<<nBlocks, 256, 0, stream>>>(R_pred, R_gt, rot, partial, S);

    reduce_kernel<<<1, 1024, 0, stream>>>(partial, nBlocks, out, 1.0f / (float)B);
}

// Round 9
// 21.041 us; speedup vs baseline: 1.6647x; 1.1888x over previous
//
#include <hip/hip_runtime.h>
#include <math.h>

#define EPS_CLIP 1e-6f
#define WPB 4      // b's per wave
#define NWAVES 4   // waves per block

struct F3 { float x, y, z; };   // 12 B -> global_load_dwordx3

// SS = compile-time S (0 -> runtime S_rt)
template <int SS>
__global__ __launch_bounds__(256) void sym_loss_kernel(
    const float* __restrict__ R_pred,   // (B, 64, 3, 3)
    const float* __restrict__ R_gt,     // (B, 3, 3)
    const float* __restrict__ rot,      // (S, 3, 3)
    float* __restrict__ partial,        // (gridDim.x,)
    int S_rt)
{
    const int S    = SS ? SS : S_rt;
    const int tid  = threadIdx.x;
    const int lane = tid & 63;
    const int wid  = tid >> 6;
    const int gw   = __builtin_amdgcn_readfirstlane(blockIdx.x * NWAVES + wid);
    const int b0   = gw * WPB;

    // per-lane base: candidate `lane` of rotation b0; next b = +192 F3
    const F3* base = reinterpret_cast<const F3*>(R_pred) + ((size_t)b0 * 64 + lane) * 3;

    // ---- 3-slot register ring, prefetch distance 2 ----
    F3 A[3][3];
    #pragma unroll
    for (int r = 0; r < 3; ++r) A[0][r] = base[r];
    #pragma unroll
    for (int r = 0; r < 3; ++r) A[1][r] = base[192 + r];

    float mk[WPB];   // per-LANE max over s (no cross-lane work inside the loop)

    #pragma unroll
    for (int k = 0; k < WPB; ++k) {
        if (k + 2 < WPB) {
            #pragma unroll
            for (int r = 0; r < 3; ++r)
                A[(k + 2) % 3][r] = base[(size_t)(k + 2) * 192 + r];
        }
        const int slot = k % 3;       // compile-time after unroll
        const int b = b0 + k;         // wave-uniform

        // G: wave-uniform address -> scalar s_loads
        const float* G = R_gt + (size_t)b * 9;
        float g[9];
        #pragma unroll
        for (int e = 0; e < 9; ++e) g[e] = G[e];

        const float p[9] = { A[slot][0].x, A[slot][0].y, A[slot][0].z,
                             A[slot][1].x, A[slot][1].y, A[slot][1].z,
                             A[slot][2].x, A[slot][2].y, A[slot][2].z };

        // Q = P * G^T (27 FMA);  trace(P @ (rot_s @ G)^T) = <Q, rot_s>  (cyclic trace)
        float q[9];
        #pragma unroll
        for (int i = 0; i < 3; ++i)
            #pragma unroll
            for (int j = 0; j < 3; ++j)
                q[i * 3 + j] = fmaf(p[i * 3 + 0], g[j * 3 + 0],
                               fmaf(p[i * 3 + 1], g[j * 3 + 1],
                                    p[i * 3 + 2] * g[j * 3 + 2]));

        // 12 independent trace-dots (rot in SGPRs), balanced max tree (v_max3-fusable)
        float tr[12 > SS ? 12 : SS];
        if (SS) {
            #pragma unroll
            for (int s = 0; s < SS; ++s) {
                const float* Rs = rot + s * 9;
                float t = q[0] * Rs[0];
                #pragma unroll
                for (int e = 1; e < 9; ++e) t = fmaf(q[e], Rs[e], t);
                tr[s] = t;
            }
            float m;
            if (SS == 12) {
                const float a = fmaxf(fmaxf(tr[0], tr[1]), tr[2]);
                const float bb = fmaxf(fmaxf(tr[3], tr[4]), tr[5]);
                const float c = fmaxf(fmaxf(tr[6], tr[7]), tr[8]);
                const float d = fmaxf(fmaxf(tr[9], tr[10]), tr[11]);
                m = fmaxf(fmaxf(a, bb), fmaxf(c, d));
            } else {
                m = tr[0];
                #pragma unroll
                for (int s = 1; s < SS; ++s) m = fmaxf(m, tr[s]);
            }
            mk[k] = m;
        } else {
            float m = -1e30f;
            for (int s = 0; s < S; ++s) {
                const float* Rs = rot + s * 9;
                float t = 0.f;
                #pragma unroll
                for (int e = 0; e < 9; ++e) t = fmaf(q[e], Rs[e], t);
                m = fmaxf(m, t);
            }
            mk[k] = m;
        }
    }

    // ---- deferred cross-lane reduce: 6 rounds x 4 independent chains ----
    #pragma unroll
    for (int off = 32; off; off >>= 1) {
        #pragma unroll
        for (int k = 0; k < WPB; ++k)
            mk[k] = fmaxf(mk[k], __shfl_xor(mk[k], off));
    }

    // ---- batched acos: lanes 0..3 take one wave max each, single acosf ----
    float mv = mk[0];
    #pragma unroll
    for (int k = 1; k < WPB; ++k) mv = (lane == k) ? mk[k] : mv;
    float cosv = (mv - 1.0f) * 0.5f;
    cosv = fminf(fmaxf(cosv, -1.0f + EPS_CLIP), 1.0f - EPS_CLIP);
    float a = (lane < WPB) ? acosf(cosv) : 0.0f;  // min over (c,s) arccos == arccos(max trace)
    a += __shfl_xor(a, 1);
    a += __shfl_xor(a, 2);

    __shared__ float sLoss[NWAVES];
    if (lane == 0) sLoss[wid] = a;
    __syncthreads();
    if (tid == 0) {
        float sum = 0.f;
        #pragma unroll
        for (int i = 0; i < NWAVES; ++i) sum += sLoss[i];
        partial[blockIdx.x] = sum;
    }
}

__global__ __launch_bounds__(1024) void reduce_kernel(
    const float* __restrict__ partial, int n, float* __restrict__ out, float invB)
{
    float sum = 0.f;
    for (int i = threadIdx.x; i < n; i += 1024) sum += partial[i];
    #pragma unroll
    for (int off = 32; off; off >>= 1) sum += __shfl_xor(sum, off);
    __shared__ float ws[16];
    const int w = threadIdx.x >> 6;
    if ((threadIdx.x & 63) == 0) ws[w] = sum;
    __syncthreads();
    if (threadIdx.x == 0) {
        float t = 0.f;
        #pragma unroll
        for (int i = 0; i < 16; ++i) t += ws[i];
        out[0] = t * invB;
    }
}

extern "C" void kernel_launch(void* const* d_in, const int* in_sizes, int n_in,
                              void* d_out, int out_size, void* d_ws, size_t ws_size,
                              hipStream_t stream) {
    const float* R_pred = (const float*)d_in[0];
    const float* R_gt   = (const float*)d_in[1];
    const float* rot    = (const float*)d_in[2];
    float* out = (float*)d_out;

    const int B = in_sizes[1] / 9;                 // 32768
    const int S = in_sizes[2] / 9;                 // 12
    const int nBlocks = B / (WPB * NWAVES);        // 2048

    float* partial = (float*)d_ws;                 // nBlocks * 4 B

    if (S == 12)
        sym_loss_kernel<12><<<nBlocks, 256, 0, stream>>>(R_pred, R_gt, rot, partial, S);
    else
        sym_loss_kernel<0><<<nBlocks, 256, 0, stream>>>(R_pred, R_gt, rot, partial, S);

    reduce_kernel<<<1, 1024, 0, stream>>>(partial, nBlocks, out, 1.0f / (float)B);
}